// Round 1
// baseline (301.183 us; speedup 1.0000x reference)
//
#include <hip/hip_runtime.h>
#include <math.h>

#define NUM_BINS 20
#define NACC     (3 * NUM_BINS)   // 60: [0,20) = sum w, [20,40) = sum w*p, [40,60) = sum w*t
#define BLOCK    256
#define NBLK     1024

// w_j(p) = exp(-(p - c_j)^2 / T) = exp2(K1*p*p) * exp2(K2*p)^j * exp2(K1*c_j*c_j)
//   K1 = -1/(T*ln2), K2 = 2/(19*T*ln2), T = 0.1, c_j = j/19
__device__ __host__ constexpr float K1f() { return (float)(-1.0 / (0.1 * 0.6931471805599453)); }
__device__ __host__ constexpr float K2f() { return (float)( 2.0 / (1.9 * 0.6931471805599453)); }

__global__ __launch_bounds__(BLOCK) void ace_partial(const float* __restrict__ p,
                                                     const float* __restrict__ t,
                                                     float* __restrict__ partials,
                                                     int n4) {
    const float K1 = K1f();
    const float K2 = K2f();

    float aW[NUM_BINS], aP[NUM_BINS], aT[NUM_BINS];
#pragma unroll
    for (int j = 0; j < NUM_BINS; ++j) { aW[j] = 0.f; aP[j] = 0.f; aT[j] = 0.f; }

    const float4* __restrict__ p4 = (const float4*)p;
    const float4* __restrict__ t4 = (const float4*)t;

    int tid    = blockIdx.x * BLOCK + threadIdx.x;
    int stride = gridDim.x * BLOCK;

    for (int i = tid; i < n4; i += stride) {
        float4 pv = p4[i];
        float4 tv = t4[i];

        float pe[4] = {pv.x, pv.y, pv.z, pv.w};
        float te[4] = {tv.x, tv.y, tv.z, tv.w};

#pragma unroll
        for (int e = 0; e < 4; ++e) {
            float pp = pe[e];
            float tt = te[e];
            float u  = __builtin_amdgcn_exp2f(K1 * pp * pp);  // exp(-p^2/T)
            float G  = __builtin_amdgcn_exp2f(K2 * pp);       // exp(2p/(19T))
            float g  = u;                                     // u * G^j, j=0
#pragma unroll
            for (int j = 0; j < NUM_BINS; ++j) {
                aW[j] += g;
                aP[j]  = fmaf(g, pp, aP[j]);
                aT[j]  = fmaf(g, tt, aT[j]);
                g     *= G;
            }
        }
    }

    // Wave(64)-level tree reduction of all 60 accumulators
#pragma unroll
    for (int j = 0; j < NUM_BINS; ++j) {
#pragma unroll
        for (int off = 32; off > 0; off >>= 1) {
            aW[j] += __shfl_down(aW[j], off, 64);
            aP[j] += __shfl_down(aP[j], off, 64);
            aT[j] += __shfl_down(aT[j], off, 64);
        }
    }

    __shared__ float red[BLOCK / 64][NACC];
    int wave = threadIdx.x >> 6;
    int lane = threadIdx.x & 63;
    if (lane == 0) {
#pragma unroll
        for (int j = 0; j < NUM_BINS; ++j) {
            red[wave][j]                = aW[j];
            red[wave][NUM_BINS + j]     = aP[j];
            red[wave][2 * NUM_BINS + j] = aT[j];
        }
    }
    __syncthreads();

    if (threadIdx.x < NACC) {
        float s = 0.f;
#pragma unroll
        for (int w = 0; w < BLOCK / 64; ++w) s += red[w][threadIdx.x];
        partials[blockIdx.x * NACC + threadIdx.x] = s;
    }
}

__global__ __launch_bounds__(1024) void ace_final(const float* __restrict__ partials,
                                                  float* __restrict__ out) {
    const float K1 = K1f();

    __shared__ float red[NACC][16];
    __shared__ float sums[NACC];
    int tid = threadIdx.x;

    if (tid < NACC * 16) {
        int j = tid >> 4;
        int k = tid & 15;
        float s = 0.f;
        for (int b = k; b < NBLK; b += 16) s += partials[b * NACC + j];
        red[j][k] = s;
    }
    __syncthreads();

    if (tid < NACC) {
        float s = 0.f;
#pragma unroll
        for (int k = 0; k < 16; ++k) s += red[tid][k];
        sums[tid] = s;
    }
    __syncthreads();

    if (tid == 0) {
        float acc = 0.f;
        for (int j = 0; j < NUM_BINS; ++j) {
            float c    = (float)j / 19.0f;
            float A    = __builtin_amdgcn_exp2f(K1 * c * c);  // exp(-c^2/T)
            float wsum = A * sums[j];
            float denom = wsum + 1e-8f;
            float e    = (A * sums[NUM_BINS + j]) / denom;
            float o    = (A * sums[2 * NUM_BINS + j]) / denom;
            float contrib = (wsum == 0.0f) ? 0.0f : fabsf(e - o);
            acc += contrib;
        }
        out[0] = acc / (float)NUM_BINS;
    }
}

extern "C" void kernel_launch(void* const* d_in, const int* in_sizes, int n_in,
                              void* d_out, int out_size, void* d_ws, size_t ws_size,
                              hipStream_t stream) {
    const float* preds   = (const float*)d_in[0];
    const float* targets = (const float*)d_in[1];
    float* out           = (float*)d_out;
    float* partials      = (float*)d_ws;   // NBLK * NACC floats = 240 KB

    int n  = in_sizes[0];
    int n4 = n >> 2;   // N = 32*1024*1024, divisible by 4

    ace_partial<<<NBLK, BLOCK, 0, stream>>>(preds, targets, partials, n4);
    ace_final<<<1, 1024, 0, stream>>>(partials, out);
}